// Round 1
// baseline (184.141 us; speedup 1.0000x reference)
//
#include <hip/hip_runtime.h>

// PatchEmbeder: x[B,C,P,16,16] -> transpose/reshape [B*P, 768] -> @W1+b1 -> @W2+b2 -> @W3+b3
//               -> concat cls row -> + pos_enc.   Output [128, 197, 768] fp32.
// Strategy: bf16 MFMA (16x16x32) for all three matmuls; prep kernel builds transposed
// bf16 weights + fused (b3+pos_enc) table; main kernel is memory-bound (~155 MB HBM).

#define BATCH 128
#define CH    3
#define NP    196
#define PIX   256          // 16*16
#define K1    768          // CH*PIX
#define N1    32
#define N2    64
#define EMB   768
#define TM    32           // rows per block; 25088/32 = 784 blocks

typedef __bf16 bf16x8 __attribute__((ext_vector_type(8)));
typedef float  f32x4  __attribute__((ext_vector_type(4)));

// workspace byte offsets (all 16B aligned)
#define W1T_OFF  0                       // 768*32*2  = 49152
#define W2T_OFF  49152                   // 32*64*2   = 4096
#define W3T_OFF  (49152 + 4096)          // 53248; 64*768*2 = 98304
#define POSB_OFF (53248 + 98304)         // 151552; 197*768*4 = 605184

// ---------------------------------------------------------------------------
// prep: transposed bf16 weights, fused bias+pos table, cls rows of output
// ---------------------------------------------------------------------------
__global__ void patchembed_prep(const float* __restrict__ W1, const float* __restrict__ W2,
                                const float* __restrict__ W3, const float* __restrict__ b3,
                                const float* __restrict__ cls, const float* __restrict__ pos,
                                __bf16* __restrict__ w1t, __bf16* __restrict__ w2t,
                                __bf16* __restrict__ w3t, float* __restrict__ posb,
                                float* __restrict__ out)
{
    int i = blockIdx.x * blockDim.x + threadIdx.x;
    const int T1 = K1 * N1;            // 24576
    const int T2 = T1 + N1 * N2;       // 26624
    const int T3 = T2 + N2 * EMB;      // 75776
    const int T4 = T3 + 197 * EMB;     // 227072
    const int T5 = T4 + BATCH * EMB;   // 325376

    if (i < T1) {                      // w1t[n][k] = W1[k][n]
        int n = i / K1, k = i - n * K1;
        w1t[i] = (__bf16)W1[k * N1 + n];
    } else if (i < T2) {               // w2t[n][k] = W2[k][n]
        int j = i - T1;
        int n = j / N1, k = j - n * N1;
        w2t[j] = (__bf16)W2[k * N2 + n];
    } else if (i < T3) {               // w3t[n][k] = W3[k][n]
        int j = i - T2;
        int n = j / N2, k = j - n * N2;
        w3t[j] = (__bf16)W3[k * EMB + n];
    } else if (i < T4) {               // posb[0][c] = cls+pos0 ; posb[r][c] = b3+pos[r]
        int j = i - T3;
        int r = j / EMB, c = j - r * EMB;
        float base = (r == 0) ? cls[c] : b3[c];
        posb[j] = base + pos[j];
    } else if (i < T5) {               // cls rows of output: out[b][0][c]
        int j = i - T4;
        int b = j / EMB, c = j - b * EMB;
        out[b * (197 * EMB) + c] = cls[c] + pos[c];
    }
}

// ---------------------------------------------------------------------------
// main: fused mm1+mm2+mm3 + epilogue, 32 rows per block, 4 waves
// MFMA 16x16x32 bf16 layouts (verified m89/m120):
//   A: m = lane&15, k = (lane>>4)*8 + j   (8 contiguous k -> 16B load)
//   B: n = lane&15, k = (lane>>4)*8 + j
//   C: col = lane&15, row = (lane>>4)*4 + reg
// ---------------------------------------------------------------------------
__global__ __launch_bounds__(256) void patchembed_main(
    const float* __restrict__ X,      // [B][C][P][256] fp32
    const float* __restrict__ b1,
    const float* __restrict__ b2,
    const __bf16* __restrict__ w1t,   // [32][768]
    const __bf16* __restrict__ w2t,   // [64][32]
    const __bf16* __restrict__ w3t,   // [768][64]
    const float* __restrict__ posb,   // [197][768]
    float* __restrict__ out)          // [B][197][768]
{
    __shared__ __align__(16) __bf16 h1s[TM][40];   // 32 cols + pad (80B stride, 16B mult)
    __shared__ __align__(16) __bf16 h2s[TM][72];   // 64 cols + pad (144B stride, 16B mult)

    const int tid  = threadIdx.x;
    const int wv   = tid >> 6;
    const int lane = tid & 63;
    const int l15  = lane & 15;
    const int quad = lane >> 4;
    const int r0   = blockIdx.x * TM;

    // ---------------- mm1: H1[32x32] = X@W1 ; wave -> tile (mi = wv>>1, ni = wv&1)
    {
        const int mi = wv >> 1;
        const int ni = wv & 1;
        const int m   = mi * 16 + l15;
        const int row = r0 + m;
        const int b   = row / NP;
        const int p   = row - b * NP;
        const int base0 = ((b * CH) * NP + p) * PIX;    // channel 0 base; +c*NP*PIX per channel
        const __bf16* wrow = w1t + (ni * 16 + l15) * K1;

        f32x4 acc = {0.f, 0.f, 0.f, 0.f};
        #pragma unroll 4
        for (int kb = 0; kb < 24; ++kb) {
            const int c      = kb >> 3;
            const int within = (kb & 7) * 32 + quad * 8;   // stays inside one 256-chunk
            const float4* xp = (const float4*)(X + base0 + c * (NP * PIX) + within);
            float4 u = xp[0];
            float4 v = xp[1];
            bf16x8 a;
            a[0] = (__bf16)u.x; a[1] = (__bf16)u.y; a[2] = (__bf16)u.z; a[3] = (__bf16)u.w;
            a[4] = (__bf16)v.x; a[5] = (__bf16)v.y; a[6] = (__bf16)v.z; a[7] = (__bf16)v.w;
            bf16x8 bf = *(const bf16x8*)(wrow + kb * 32 + quad * 8);
            acc = __builtin_amdgcn_mfma_f32_16x16x32_bf16(a, bf, acc, 0, 0, 0);
        }
        const float bias = b1[ni * 16 + l15];
        #pragma unroll
        for (int r = 0; r < 4; ++r)
            h1s[mi * 16 + quad * 4 + r][ni * 16 + l15] = (__bf16)(acc[r] + bias);
    }
    __syncthreads();

    // ---------------- mm2: H2[32x64] = H1@W2 ; wave wv -> n-tile wv, both m-tiles
    {
        bf16x8 bf = *(const bf16x8*)(w2t + (wv * 16 + l15) * N1 + quad * 8);
        bf16x8 a0 = *(const bf16x8*)(&h1s[l15][quad * 8]);
        bf16x8 a1 = *(const bf16x8*)(&h1s[16 + l15][quad * 8]);
        f32x4 z = {0.f, 0.f, 0.f, 0.f};
        f32x4 acc0 = __builtin_amdgcn_mfma_f32_16x16x32_bf16(a0, bf, z, 0, 0, 0);
        f32x4 acc1 = __builtin_amdgcn_mfma_f32_16x16x32_bf16(a1, bf, z, 0, 0, 0);
        const float bias = b2[wv * 16 + l15];
        #pragma unroll
        for (int r = 0; r < 4; ++r) {
            h2s[quad * 4 + r][wv * 16 + l15]      = (__bf16)(acc0[r] + bias);
            h2s[16 + quad * 4 + r][wv * 16 + l15] = (__bf16)(acc1[r] + bias);
        }
    }
    __syncthreads();

    // ---------------- mm3: OUT[32x768] = H2@W3 (+ posb epilogue)
    {
        bf16x8 a00 = *(const bf16x8*)(&h2s[l15][quad * 8]);
        bf16x8 a01 = *(const bf16x8*)(&h2s[l15][32 + quad * 8]);
        bf16x8 a10 = *(const bf16x8*)(&h2s[16 + l15][quad * 8]);
        bf16x8 a11 = *(const bf16x8*)(&h2s[16 + l15][32 + quad * 8]);

        int obase[2][4];
        int pbase[2][4];
        #pragma unroll
        for (int mi2 = 0; mi2 < 2; ++mi2)
            #pragma unroll
            for (int r = 0; r < 4; ++r) {
                const int row = r0 + mi2 * 16 + quad * 4 + r;
                const int b = row / NP;
                const int p = row - b * NP;
                obase[mi2][r] = (b * 197 + p + 1) * EMB;
                pbase[mi2][r] = (p + 1) * EMB;
            }

        for (int t = 0; t < 12; ++t) {          // 48 n-tiles / 4 waves
            const int nt  = wv * 12 + t;
            const int col = nt * 16 + l15;
            const __bf16* wr = w3t + col * N2;
            bf16x8 bf0 = *(const bf16x8*)(wr + quad * 8);
            bf16x8 bf1 = *(const bf16x8*)(wr + 32 + quad * 8);
            f32x4 z = {0.f, 0.f, 0.f, 0.f};
            f32x4 c0 = __builtin_amdgcn_mfma_f32_16x16x32_bf16(a00, bf0, z, 0, 0, 0);
            c0       = __builtin_amdgcn_mfma_f32_16x16x32_bf16(a01, bf1, c0, 0, 0, 0);
            f32x4 c1 = __builtin_amdgcn_mfma_f32_16x16x32_bf16(a10, bf0, z, 0, 0, 0);
            c1       = __builtin_amdgcn_mfma_f32_16x16x32_bf16(a11, bf1, c1, 0, 0, 0);
            #pragma unroll
            for (int r = 0; r < 4; ++r) {
                out[obase[0][r] + col] = c0[r] + posb[pbase[0][r] + col];
                out[obase[1][r] + col] = c1[r] + posb[pbase[1][r] + col];
            }
        }
    }
}

extern "C" void kernel_launch(void* const* d_in, const int* in_sizes, int n_in,
                              void* d_out, int out_size, void* d_ws, size_t ws_size,
                              hipStream_t stream)
{
    const float* X   = (const float*)d_in[0];
    const float* W1  = (const float*)d_in[1];
    const float* b1  = (const float*)d_in[2];
    const float* W2  = (const float*)d_in[3];
    const float* b2  = (const float*)d_in[4];
    const float* W3  = (const float*)d_in[5];
    const float* b3  = (const float*)d_in[6];
    const float* cls = (const float*)d_in[7];
    const float* pos = (const float*)d_in[8];
    float* out = (float*)d_out;

    char* ws = (char*)d_ws;
    __bf16* w1t = (__bf16*)(ws + W1T_OFF);
    __bf16* w2t = (__bf16*)(ws + W2T_OFF);
    __bf16* w3t = (__bf16*)(ws + W3T_OFF);
    float*  posb = (float*)(ws + POSB_OFF);

    // 325376 total prep work items
    patchembed_prep<<<1271, 256, 0, stream>>>(W1, W2, W3, b3, cls, pos,
                                              w1t, w2t, w3t, posb, out);
    patchembed_main<<<784, 256, 0, stream>>>(X, b1, b2, w1t, w2t, w3t, posb, out);
}

// Round 4
// 183.660 us; speedup vs baseline: 1.0026x; 1.0026x over previous
//
#include <hip/hip_runtime.h>

// PatchEmbeder: x[B,C,P,16,16] -> [B*P,768] @W1+b1 @W2+b2 @W3+b3 -> +cls/pos.
// v2b: identical design to v2 (rounds 2/3 were infra failures, no HW data) but
// with __builtin_nontemporal_store replaced by plain stores — the only construct
// new vs the v1 source that ran cleanly. 16-row blocks (1568), mm1 K-split across
// 4 waves (LDS fp32 reduce), mm3 cols split 4-ways/wave -> 6272 waves (24.5/CU).
// v1 was latency-bound: Occ 26%, VALUBusy 8%, MfmaUtil 1.8%, 1.8 TB/s.

#define BATCH 128
#define CH    3
#define NP    196
#define PIX   256          // 16*16
#define K1    768          // CH*PIX
#define N1    32
#define N2    64
#define EMB   768

typedef __bf16 bf16x8 __attribute__((ext_vector_type(8)));
typedef float  f32x4  __attribute__((ext_vector_type(4)));

// workspace byte offsets (all 16B aligned)
#define W1T_OFF  0                       // 768*32*2  = 49152
#define W2T_OFF  49152                   // 32*64*2   = 4096
#define W3T_OFF  (49152 + 4096)          // 53248; 64*768*2 = 98304
#define POSB_OFF (53248 + 98304)         // 151552; 197*768*4 = 605184

// ---------------------------------------------------------------------------
// prep: transposed bf16 weights, fused bias+pos table, cls rows of output
// ---------------------------------------------------------------------------
__global__ void patchembed_prep(const float* __restrict__ W1, const float* __restrict__ W2,
                                const float* __restrict__ W3, const float* __restrict__ b3,
                                const float* __restrict__ cls, const float* __restrict__ pos,
                                __bf16* __restrict__ w1t, __bf16* __restrict__ w2t,
                                __bf16* __restrict__ w3t, float* __restrict__ posb,
                                float* __restrict__ out)
{
    int i = blockIdx.x * blockDim.x + threadIdx.x;
    const int T1 = K1 * N1;            // 24576
    const int T2 = T1 + N1 * N2;       // 26624
    const int T3 = T2 + N2 * EMB;      // 75776
    const int T4 = T3 + 197 * EMB;     // 227072
    const int T5 = T4 + BATCH * EMB;   // 325376

    if (i < T1) {                      // w1t[n][k] = W1[k][n]
        int n = i / K1, k = i - n * K1;
        w1t[i] = (__bf16)W1[k * N1 + n];
    } else if (i < T2) {               // w2t[n][k] = W2[k][n]
        int j = i - T1;
        int n = j / N1, k = j - n * N1;
        w2t[j] = (__bf16)W2[k * N2 + n];
    } else if (i < T3) {               // w3t[n][k] = W3[k][n]
        int j = i - T2;
        int n = j / N2, k = j - n * N2;
        w3t[j] = (__bf16)W3[k * EMB + n];
    } else if (i < T4) {               // posb[0][c] = cls+pos0 ; posb[r][c] = b3+pos[r]
        int j = i - T3;
        int r = j / EMB, c = j - r * EMB;
        float base = (r == 0) ? cls[c] : b3[c];
        posb[j] = base + pos[j];
    } else if (i < T5) {               // cls rows of output: out[b][0][c]
        int j = i - T4;
        int b = j / EMB, c = j - b * EMB;
        out[b * (197 * EMB) + c] = cls[c] + pos[c];
    }
}

// ---------------------------------------------------------------------------
// main v2: 16 rows per block, 4 waves.
//  phase1: mm1 K-split — wave wv does ksteps [wv*6, wv*6+6), partial H1 -> LDS fp32
//  phase2: reduce 4 partials + b1 -> A-frag; mm2 (one MFMA/wave) + b2 -> H2 slab LDS
//  phase3: mm3 — wave wv covers cols [wv*192, wv*192+192) + posb epilogue
// MFMA 16x16x32 bf16 layouts (verified m89/m120):
//   A: m = lane&15, k = (lane>>4)*8 + j
//   B: n = lane&15, k = (lane>>4)*8 + j
//   C: col = lane&15, row = (lane>>4)*4 + reg
// ---------------------------------------------------------------------------
__global__ __launch_bounds__(256) void patchembed_main(
    const float* __restrict__ X,      // [B][C][P][256] fp32
    const float* __restrict__ b1,
    const float* __restrict__ b2,
    const __bf16* __restrict__ w1t,   // [32][768]
    const __bf16* __restrict__ w2t,   // [64][32]
    const __bf16* __restrict__ w3t,   // [768][64]
    const float* __restrict__ posb,   // [197][768]
    float* __restrict__ out)          // [B][197][768]
{
    __shared__ __align__(16) float  h1p[4][16][36];   // per-wave mm1 partials (+pad, 16B-mult)
    __shared__ __align__(16) __bf16 h2s[16][72];      // H2 bf16 (+pad, 16B-mult stride)

    const int tid  = threadIdx.x;
    const int wv   = tid >> 6;
    const int lane = tid & 63;
    const int l15  = lane & 15;
    const int q    = lane >> 4;
    const int r0   = blockIdx.x * 16;

    // ---------------- phase 1: partial H1[16x32] over K=192 per wave
    {
        const int xrow  = r0 + l15;
        const int b     = xrow / NP;
        const int p     = xrow - b * NP;
        const int base0 = ((b * CH) * NP + p) * PIX;       // channel-0 base (floats)
        const __bf16* w0r = w1t + l15 * K1;                // n-tile 0, n = l15
        const __bf16* w1r = w1t + (16 + l15) * K1;         // n-tile 1, n = 16+l15

        f32x4 acc0 = {0.f, 0.f, 0.f, 0.f};
        f32x4 acc1 = {0.f, 0.f, 0.f, 0.f};
        #pragma unroll
        for (int t = 0; t < 6; ++t) {
            const int kb  = wv * 6 + t;
            const int c   = kb >> 3;
            const int off = (kb & 7) * 32 + q * 8;
            const float4* xp = (const float4*)(X + base0 + c * (NP * PIX) + off);
            float4 u = xp[0];
            float4 v = xp[1];
            bf16x8 a;
            a[0] = (__bf16)u.x; a[1] = (__bf16)u.y; a[2] = (__bf16)u.z; a[3] = (__bf16)u.w;
            a[4] = (__bf16)v.x; a[5] = (__bf16)v.y; a[6] = (__bf16)v.z; a[7] = (__bf16)v.w;
            bf16x8 f0 = *(const bf16x8*)(w0r + kb * 32 + q * 8);
            bf16x8 f1 = *(const bf16x8*)(w1r + kb * 32 + q * 8);
            acc0 = __builtin_amdgcn_mfma_f32_16x16x32_bf16(a, f0, acc0, 0, 0, 0);
            acc1 = __builtin_amdgcn_mfma_f32_16x16x32_bf16(a, f1, acc1, 0, 0, 0);
        }
        #pragma unroll
        for (int r = 0; r < 4; ++r) {
            h1p[wv][q * 4 + r][l15]      = acc0[r];
            h1p[wv][q * 4 + r][16 + l15] = acc1[r];
        }
    }
    __syncthreads();

    // ---------------- phase 2: reduce + b1 -> H1 A-frag; mm2; + b2 -> h2s
    {
        f32x4 s0 = {0.f, 0.f, 0.f, 0.f};
        f32x4 s1 = {0.f, 0.f, 0.f, 0.f};
        #pragma unroll
        for (int w = 0; w < 4; ++w) {
            s0 += *(const f32x4*)&h1p[w][l15][q * 8];
            s1 += *(const f32x4*)&h1p[w][l15][q * 8 + 4];
        }
        s0 += *(const f32x4*)(b1 + q * 8);
        s1 += *(const f32x4*)(b1 + q * 8 + 4);
        bf16x8 a;
        #pragma unroll
        for (int j = 0; j < 4; ++j) {
            a[j]     = (__bf16)s0[j];
            a[4 + j] = (__bf16)s1[j];
        }
        bf16x8 f = *(const bf16x8*)(w2t + (wv * 16 + l15) * N1 + q * 8);
        f32x4 z = {0.f, 0.f, 0.f, 0.f};
        f32x4 h2 = __builtin_amdgcn_mfma_f32_16x16x32_bf16(a, f, z, 0, 0, 0);
        const float bias = b2[wv * 16 + l15];
        #pragma unroll
        for (int r = 0; r < 4; ++r)
            h2s[q * 4 + r][wv * 16 + l15] = (__bf16)(h2[r] + bias);
    }
    __syncthreads();

    // ---------------- phase 3: mm3 (192 cols per wave) + posb epilogue
    {
        bf16x8 a0 = *(const bf16x8*)(&h2s[l15][q * 8]);
        bf16x8 a1 = *(const bf16x8*)(&h2s[l15][32 + q * 8]);

        int obase[4], pbase[4];
        #pragma unroll
        for (int r = 0; r < 4; ++r) {
            const int row = r0 + q * 4 + r;
            const int b = row / NP;
            const int p = row - b * NP;
            obase[r] = (b * 197 + p + 1) * EMB;
            pbase[r] = (p + 1) * EMB;
        }

        #pragma unroll 4
        for (int t = 0; t < 12; ++t) {
            const int col = wv * 192 + t * 16 + l15;
            const __bf16* wr = w3t + col * N2;
            bf16x8 f0 = *(const bf16x8*)(wr + q * 8);
            bf16x8 f1 = *(const bf16x8*)(wr + 32 + q * 8);
            f32x4 z = {0.f, 0.f, 0.f, 0.f};
            f32x4 c0 = __builtin_amdgcn_mfma_f32_16x16x32_bf16(a0, f0, z, 0, 0, 0);
            c0       = __builtin_amdgcn_mfma_f32_16x16x32_bf16(a1, f1, c0, 0, 0, 0);
            #pragma unroll
            for (int r = 0; r < 4; ++r) {
                out[obase[0 * 4 + r] + col] = c0[r] + posb[pbase[r] + col];
            }
        }
    }
}

extern "C" void kernel_launch(void* const* d_in, const int* in_sizes, int n_in,
                              void* d_out, int out_size, void* d_ws, size_t ws_size,
                              hipStream_t stream)
{
    const float* X   = (const float*)d_in[0];
    const float* W1  = (const float*)d_in[1];
    const float* b1  = (const float*)d_in[2];
    const float* W2  = (const float*)d_in[3];
    const float* b2  = (const float*)d_in[4];
    const float* W3  = (const float*)d_in[5];
    const float* b3  = (const float*)d_in[6];
    const float* cls = (const float*)d_in[7];
    const float* pos = (const float*)d_in[8];
    float* out = (float*)d_out;

    char* ws = (char*)d_ws;
    __bf16* w1t = (__bf16*)(ws + W1T_OFF);
    __bf16* w2t = (__bf16*)(ws + W2T_OFF);
    __bf16* w3t = (__bf16*)(ws + W3T_OFF);
    float*  posb = (float*)(ws + POSB_OFF);

    patchembed_prep<<<1271, 256, 0, stream>>>(W1, W2, W3, b3, cls, pos,
                                              w1t, w2t, w3t, posb, out);
    patchembed_main<<<1568, 256, 0, stream>>>(X, b1, b2, w1t, w2t, w3t, posb, out);
}